// Round 1
// baseline (503.889 us; speedup 1.0000x reference)
//
#include <hip/hip_runtime.h>
#include <math.h>

typedef float  f32x4 __attribute__((ext_vector_type(4)));
typedef short  s16x8 __attribute__((ext_vector_type(8)));
typedef unsigned short u16x8 __attribute__((ext_vector_type(8)));
typedef unsigned int   u32x4 __attribute__((ext_vector_type(4)));

constexpr int TOKENS  = 16384;
constexpr int DIM     = 4096;
constexpr int NE      = 64;
constexpr int TOPK    = 8;
constexpr int KB      = 32;          // k per chunk
constexpr int NIT     = DIM / KB;    // 128 chunks
constexpr int LISTCAP = 16384;
constexpr float GAPTH = 1e-4f;       // flag threshold (phase-1 err ~2e-5)

// precomputed W bf16 planes: [it][T][lane][8] ushorts, hi plane then lo plane
constexpr unsigned WARR_U16   = (unsigned)NIT * 4 * 64 * 8;                 // 262144
constexpr size_t   WS_INT_OFF = (size_t)WARR_U16 * 2 * sizeof(unsigned short); // 1 MiB
constexpr size_t   WS_NEEDED  = WS_INT_OFF + sizeof(int) * (size_t)(16 + LISTCAP);

__device__ __forceinline__ unsigned short bf_rne(float f) {
    unsigned u = __float_as_uint(f);
    u += 0x7FFFu + ((u >> 16) & 1u);
    return (unsigned short)(u >> 16);
}
__device__ __forceinline__ float bf_f32(unsigned short h) {
    return __uint_as_float(((unsigned)h) << 16);
}
// pack two floats -> (hi bf16 pair, lo bf16 pair); identical numerics to prior kernel
__device__ __forceinline__ uint2 cvt_pair(float f0, float f1) {
    unsigned short h0 = bf_rne(f0);
    unsigned short h1 = bf_rne(f1);
    uint2 r;
    r.x = (unsigned)h0 | ((unsigned)h1 << 16);
    r.y = (unsigned)bf_rne(f0 - bf_f32(h0)) | ((unsigned)bf_rne(f1 - bf_f32(h1)) << 16);
    return r;
}
union Cvt { u32x4 u; s16x8 s; };

// ---- W -> bf16 hi/lo planes, arranged in exact B-fragment order ----------
// elem index = ((it*4 + T)*64 + lane)*8 + j ; lane=(lq,ln): expert=16T+ln, k=32it+8lq+j
__global__ __launch_bounds__(256)
void wconv_kernel(const float* __restrict__ W, unsigned short* __restrict__ wpk,
                  int* __restrict__ wsI)
{
    unsigned tid = blockIdx.x * 256u + threadIdx.x;
    if (tid == 0) wsI[0] = 0;                 // counter zero (wconv precedes gemm)
    unsigned j    = tid & 7u;
    unsigned lane = (tid >> 3) & 63u;
    unsigned T    = (tid >> 9) & 3u;
    unsigned it   = tid >> 11;
    unsigned e = 16u * T + (lane & 15u);
    unsigned k = 32u * it + 8u * (lane >> 4) + j;
    float v = W[(size_t)e * DIM + k];
    unsigned short h = bf_rne(v);
    wpk[tid]            = h;
    wpk[WARR_U16 + tid] = bf_rne(v - bf_f32(h));
}

// ---- main: barrier-free streaming GEMM + top-k --------------------------
// grid 512 x 128 threads (2 waves). wave w: 16 tokens, all 64 experts.
// A-frag loaded straight from global (lane l: row ln, k=8lq..+7 contiguous).
// B-frag loaded straight from precomputed wpk (L2-resident, coalesced 1KB/instr).
__global__ __launch_bounds__(128, 2)
void gemm_topk_v2(const float* __restrict__ x,
                  const unsigned short* __restrict__ wpk,
                  float* __restrict__ out, int* __restrict__ wsI)
{
    __shared__ float ls[32][NE + 4];

    const int t    = threadIdx.x;
    const int w    = t >> 6;
    const int l    = t & 63;
    const int lq   = l >> 4;
    const int ln   = l & 15;
    const int tok0 = blockIdx.x * 32;

    const float* xg = x + (size_t)(tok0 + 16 * w + ln) * DIM + 8 * lq;
    const s16x8* bhp = (const s16x8*)wpk + l;
    const s16x8* blp = bhp + (WARR_U16 / 8);

    f32x4 acc[4];
#pragma unroll
    for (int T = 0; T < 4; ++T) acc[T] = (f32x4){0.f, 0.f, 0.f, 0.f};

    // x pipeline depth 2
    float4 xa0 = *(const float4*)(xg + 0);
    float4 xa1 = *(const float4*)(xg + 4);
    float4 xb0 = *(const float4*)(xg + KB + 0);
    float4 xb1 = *(const float4*)(xg + KB + 4);
    // B pipeline depth 1
    s16x8 bh0 = bhp[0], bh1 = bhp[64], bh2 = bhp[128], bh3 = bhp[192];
    s16x8 bl0 = blp[0], bl1 = blp[64], bl2 = blp[128], bl3 = blp[192];

#pragma unroll 2
    for (int it = 0; it < NIT; ++it) {
        const int itx = (it + 2 < NIT) ? it + 2 : NIT - 1;
        const float* xp = xg + (size_t)KB * itx;
        float4 xn0 = *(const float4*)(xp + 0);
        float4 xn1 = *(const float4*)(xp + 4);

        const int itn = (it + 1 < NIT) ? it + 1 : NIT - 1;
        const s16x8* nhp = bhp + itn * 256;
        const s16x8* nlp = blp + itn * 256;
        s16x8 nh0 = nhp[0], nh1 = nhp[64], nh2 = nhp[128], nh3 = nhp[192];
        s16x8 nl0 = nlp[0], nl1 = nlp[64], nl2 = nlp[128], nl3 = nlp[192];

        // fp32 -> bf16 hi/lo, in registers (no LDS round-trip)
        uint2 p0 = cvt_pair(xa0.x, xa0.y);
        uint2 p1 = cvt_pair(xa0.z, xa0.w);
        uint2 p2 = cvt_pair(xa1.x, xa1.y);
        uint2 p3 = cvt_pair(xa1.z, xa1.w);
        Cvt ch, cl;
        ch.u = (u32x4){p0.x, p1.x, p2.x, p3.x};
        cl.u = (u32x4){p0.y, p1.y, p2.y, p3.y};
        s16x8 ah = ch.s, al = cl.s;

        // bf16x3: ah*bh + ah*bl + al*bh ; groups of 4 independent accs
        acc[0] = __builtin_amdgcn_mfma_f32_16x16x32_bf16(ah, bh0, acc[0], 0, 0, 0);
        acc[1] = __builtin_amdgcn_mfma_f32_16x16x32_bf16(ah, bh1, acc[1], 0, 0, 0);
        acc[2] = __builtin_amdgcn_mfma_f32_16x16x32_bf16(ah, bh2, acc[2], 0, 0, 0);
        acc[3] = __builtin_amdgcn_mfma_f32_16x16x32_bf16(ah, bh3, acc[3], 0, 0, 0);
        acc[0] = __builtin_amdgcn_mfma_f32_16x16x32_bf16(ah, bl0, acc[0], 0, 0, 0);
        acc[1] = __builtin_amdgcn_mfma_f32_16x16x32_bf16(ah, bl1, acc[1], 0, 0, 0);
        acc[2] = __builtin_amdgcn_mfma_f32_16x16x32_bf16(ah, bl2, acc[2], 0, 0, 0);
        acc[3] = __builtin_amdgcn_mfma_f32_16x16x32_bf16(ah, bl3, acc[3], 0, 0, 0);
        acc[0] = __builtin_amdgcn_mfma_f32_16x16x32_bf16(al, bh0, acc[0], 0, 0, 0);
        acc[1] = __builtin_amdgcn_mfma_f32_16x16x32_bf16(al, bh1, acc[1], 0, 0, 0);
        acc[2] = __builtin_amdgcn_mfma_f32_16x16x32_bf16(al, bh2, acc[2], 0, 0, 0);
        acc[3] = __builtin_amdgcn_mfma_f32_16x16x32_bf16(al, bh3, acc[3], 0, 0, 0);

        bh0 = nh0; bh1 = nh1; bh2 = nh2; bh3 = nh3;
        bl0 = nl0; bl1 = nl1; bl2 = nl2; bl3 = nl3;
        xa0 = xb0; xa1 = xb1; xb0 = xn0; xb1 = xn1;
    }

    // D layout (m89-verified): col = ln, row = 4*lq + r
#pragma unroll
    for (int T = 0; T < 4; ++T)
#pragma unroll
        for (int r = 0; r < 4; ++r)
            ls[16 * w + 4 * lq + r][16 * T + ln] = acc[T][r];
    __syncthreads();

    // top-9 scan + gap flag + fp32 softmax: one thread per token, both waves active
    if ((t & 3) == 0) {
        const int ti  = t >> 2;           // 0..31
        const int tok = tok0 + ti;
        float v[9]; int idx[9];
#pragma unroll
        for (int j = 0; j < 9; ++j) {
            float best = -3.4e38f; int bi = 0;
            for (int e = 0; e < NE; ++e) {
                float q = ls[ti][e];
                if (q > best) { best = q; bi = e; }   // lowest index wins ties
            }
            v[j] = best; idx[j] = bi;
            ls[ti][bi] = -3.4e38f;
        }
        bool flag = false;
#pragma unroll
        for (int j = 0; j < 8; ++j)
            if (v[j] - v[j + 1] < GAPTH) flag = true;

        float m = v[0], s = 0.f, ex[8];
#pragma unroll
        for (int j = 0; j < 8; ++j) { ex[j] = expf(v[j] - m); s += ex[j]; }
        float inv = 1.f / s;
#pragma unroll
        for (int j = 0; j < 8; ++j) {
            out[(size_t)tok * TOPK + j] = ex[j] * inv;
            out[(size_t)TOKENS * TOPK + (size_t)tok * TOPK + j] = (float)idx[j];
        }
        if (flag) {
            int pos = atomicAdd(wsI, 1);
            if (pos < LISTCAP) wsI[16 + pos] = tok;
        }
    }
}

// exact fp64 recompute for flagged tokens (no MFMA-layout risk)
__global__ __launch_bounds__(256)
void refine_kernel(const float* __restrict__ x, const float* __restrict__ W,
                   float* __restrict__ out, const int* __restrict__ wsI)
{
    __shared__ float  xr[DIM];     // 16 KB
    __shared__ double pt[256];
    __shared__ double lg[NE];

    int cnt = wsI[0];
    if (cnt > LISTCAP) cnt = LISTCAP;
    const int t = threadIdx.x;

    for (int g = blockIdx.x; g < cnt; g += gridDim.x) {
        const int tok = wsI[16 + g];
        __syncthreads();   // previous iteration fully done before restaging
        for (int i = t; i < DIM / 4; i += 256)
            *(float4*)&xr[4 * i] = *(const float4*)&x[(size_t)tok * DIM + 4 * i];
        __syncthreads();

        const int e  = t & 63;
        const int ks = t >> 6;
        const float* wp = W + (size_t)e * DIM + ks * 1024;
        const float* xp = xr + ks * 1024;
        double p = 0.0;
        for (int i = 0; i < 256; ++i) {
            float4 wv = *(const float4*)&wp[4 * i];
            float4 xv = *(const float4*)&xp[4 * i];
            p = fma((double)xv.x, (double)wv.x, p);
            p = fma((double)xv.y, (double)wv.y, p);
            p = fma((double)xv.z, (double)wv.z, p);
            p = fma((double)xv.w, (double)wv.w, p);
        }
        pt[t] = p;
        __syncthreads();
        if (t < NE)
            lg[t] = ((pt[t] + pt[t + 64]) + pt[t + 128]) + pt[t + 192];  // fixed order
        __syncthreads();
        if (t == 0) {
            double vv[8]; int ii[8];
#pragma unroll
            for (int j = 0; j < 8; ++j) {
                double best = -1e300; int bi = 0;
                for (int e2 = 0; e2 < NE; ++e2) {
                    double q = lg[e2];
                    if (q > best) { best = q; bi = e2; }
                }
                vv[j] = best; ii[j] = bi;
                lg[bi] = -1e300;
            }
            float pf[8], ex[8], s = 0.f;
#pragma unroll
            for (int j = 0; j < 8; ++j) pf[j] = (float)vv[j];
            float m = pf[0];
#pragma unroll
            for (int j = 0; j < 8; ++j) { ex[j] = expf(pf[j] - m); s += ex[j]; }
            float inv = 1.f / s;
#pragma unroll
            for (int j = 0; j < 8; ++j) {
                out[(size_t)tok * TOPK + j] = ex[j] * inv;
                out[(size_t)TOKENS * TOPK + (size_t)tok * TOPK + j] = (float)ii[j];
            }
        }
    }
}

// =================== fallback (previous verified path) ====================
__global__ void zero_cnt_kernel(int* wsI) { if (threadIdx.x == 0) wsI[0] = 0; }

__global__ __launch_bounds__(256)
void gemm_topk_old(const float* __restrict__ x, const float* __restrict__ W,
                   float* __restrict__ out, int* __restrict__ wsI)
{
    __shared__ __align__(16) unsigned short frag[8192];
    __shared__ float ls[64][NE + 4];

    const int t    = threadIdx.x;
    const int tok0 = blockIdx.x * 64;

    const int srow = t >> 2;
    const int sq   = t & 3;
    const int sn   = srow & 15;
    const int sT   = srow >> 4;
    const int sdst = sT * 512 + (16 * sq + (sn ^ (2 * sq))) * 8;
    const float* xg = x + (size_t)(tok0 + srow) * DIM + 8 * sq;
    const float* wg = W + (size_t)srow * DIM + 8 * sq;

    const int w  = t >> 6;
    const int l  = t & 63;
    const int lq = l >> 4;
    const int ln = l & 15;
    const int fo = (16 * lq + (ln ^ (2 * lq))) * 8;

    f32x4 acc[4];
#pragma unroll
    for (int T = 0; T < 4; ++T) acc[T] = (f32x4){0.f, 0.f, 0.f, 0.f};

    float4 xa = *(const float4*)xg;
    float4 xb = *(const float4*)(xg + 4);
    float4 wa = *(const float4*)wg;
    float4 wb = *(const float4*)(wg + 4);

    for (int it = 0; it < NIT; ++it) {
        __syncthreads();
        {
            float vx[8] = {xa.x, xa.y, xa.z, xa.w, xb.x, xb.y, xb.z, xb.w};
            float vw[8] = {wa.x, wa.y, wa.z, wa.w, wb.x, wb.y, wb.z, wb.w};
            u16x8 vxh, vxl, vwh, vwl;
#pragma unroll
            for (int j = 0; j < 8; ++j) {
                unsigned short h1 = bf_rne(vx[j]);
                vxh[j] = h1;
                vxl[j] = bf_rne(vx[j] - bf_f32(h1));
                unsigned short h2 = bf_rne(vw[j]);
                vwh[j] = h2;
                vwl[j] = bf_rne(vw[j] - bf_f32(h2));
            }
            *(u16x8*)&frag[   0 + sdst] = vxh;
            *(u16x8*)&frag[2048 + sdst] = vxl;
            *(u16x8*)&frag[4096 + sdst] = vwh;
            *(u16x8*)&frag[6144 + sdst] = vwl;
        }
        __syncthreads();
        if (it + 1 < NIT) {
            const float* xp = xg + (size_t)(it + 1) * KB;
            const float* wp = wg + (size_t)(it + 1) * KB;
            xa = *(const float4*)xp;  xb = *(const float4*)(xp + 4);
            wa = *(const float4*)wp;  wb = *(const float4*)(wp + 4);
        }
        s16x8 ah = *(const s16x8*)&frag[   0 + w * 512 + fo];
        s16x8 al = *(const s16x8*)&frag[2048 + w * 512 + fo];
#pragma unroll
        for (int T = 0; T < 4; ++T) {
            s16x8 bh = *(const s16x8*)&frag[4096 + T * 512 + fo];
            s16x8 bl = *(const s16x8*)&frag[6144 + T * 512 + fo];
            acc[T] = __builtin_amdgcn_mfma_f32_16x16x32_bf16(ah, bh, acc[T], 0, 0, 0);
            acc[T] = __builtin_amdgcn_mfma_f32_16x16x32_bf16(ah, bl, acc[T], 0, 0, 0);
            acc[T] = __builtin_amdgcn_mfma_f32_16x16x32_bf16(al, bh, acc[T], 0, 0, 0);
        }
    }

    __syncthreads();
#pragma unroll
    for (int T = 0; T < 4; ++T)
#pragma unroll
        for (int r = 0; r < 4; ++r)
            ls[16 * w + 4 * lq + r][16 * T + ln] = acc[T][r];
    __syncthreads();

    if (t < 64) {
        const int tok = tok0 + t;
        float v[9]; int idx[9];
#pragma unroll
        for (int j = 0; j < 9; ++j) {
            float best = -3.4e38f; int bi = 0;
            for (int e = 0; e < NE; ++e) {
                float q = ls[t][e];
                if (q > best) { best = q; bi = e; }
            }
            v[j] = best; idx[j] = bi;
            ls[t][bi] = -3.4e38f;
        }
        bool flag = false;
#pragma unroll
        for (int j = 0; j < 8; ++j)
            if (v[j] - v[j + 1] < GAPTH) flag = true;

        float m = v[0], s = 0.f, ex[8];
#pragma unroll
        for (int j = 0; j < 8; ++j) { ex[j] = expf(v[j] - m); s += ex[j]; }
        float inv = 1.f / s;
#pragma unroll
        for (int j = 0; j < 8; ++j) {
            out[(size_t)tok * TOPK + j] = ex[j] * inv;
            out[(size_t)TOKENS * TOPK + (size_t)tok * TOPK + j] = (float)idx[j];
        }
        if (flag) {
            int pos = atomicAdd(wsI, 1);
            if (pos < LISTCAP) wsI[16 + pos] = tok;
        }
    }
}

extern "C" void kernel_launch(void* const* d_in, const int* in_sizes, int n_in,
                              void* d_out, int out_size, void* d_ws, size_t ws_size,
                              hipStream_t stream)
{
    const float* x = (const float*)d_in[0];
    const float* W = (const float*)d_in[1];
    float* out = (float*)d_out;

    if (ws_size >= WS_NEEDED) {
        unsigned short* wpk = (unsigned short*)d_ws;
        int* wsI = (int*)((char*)d_ws + WS_INT_OFF);
        hipLaunchKernelGGL(wconv_kernel, dim3(WARR_U16 / 256), dim3(256), 0, stream, W, wpk, wsI);
        hipLaunchKernelGGL(gemm_topk_v2, dim3(TOKENS / 32), dim3(128), 0, stream, x, wpk, out, wsI);
        hipLaunchKernelGGL(refine_kernel, dim3(256), dim3(256), 0, stream, x, W, out, wsI);
    } else {
        int* wsI = (int*)d_ws;
        hipLaunchKernelGGL(zero_cnt_kernel, dim3(1), dim3(64), 0, stream, wsI);
        hipLaunchKernelGGL(gemm_topk_old, dim3(TOKENS / 64), dim3(256), 0, stream, x, W, out, wsI);
        hipLaunchKernelGGL(refine_kernel, dim3(256), dim3(256), 0, stream, x, W, out, wsI);
    }
}

// Round 2
// 489.877 us; speedup vs baseline: 1.0286x; 1.0286x over previous
//
#include <hip/hip_runtime.h>
#include <math.h>

typedef float  f32x4 __attribute__((ext_vector_type(4)));
typedef short  s16x8 __attribute__((ext_vector_type(8)));
typedef unsigned short u16x8 __attribute__((ext_vector_type(8)));
typedef unsigned int   u32x4 __attribute__((ext_vector_type(4)));

constexpr int TOKENS  = 16384;
constexpr int DIM     = 4096;
constexpr int NE      = 64;
constexpr int TOPK    = 8;
constexpr int KB      = 32;          // k per chunk
constexpr int NIT     = DIM / KB;    // 128 chunks total
constexpr int WAVES   = 8;           // within-block K-split factor
constexpr int KSL     = DIM / WAVES; // 512 floats per wave slice
constexpr int NITW    = KSL / KB;    // 16 chunks per wave
constexpr int LISTCAP = 16384;
constexpr float GAPTH = 1e-4f;       // flag threshold (phase-1 err ~2e-5)

// precomputed W bf16 planes: [it][T][lane][8] ushorts, hi plane then lo plane
constexpr unsigned WARR_U16   = (unsigned)NIT * 4 * 64 * 8;                 // 262144
constexpr size_t   WS_INT_OFF = (size_t)WARR_U16 * 2 * sizeof(unsigned short); // 1 MiB
constexpr size_t   WS_NEEDED  = WS_INT_OFF + sizeof(int) * (size_t)(16 + LISTCAP);

__device__ __forceinline__ unsigned short bf_rne(float f) {
    unsigned u = __float_as_uint(f);
    u += 0x7FFFu + ((u >> 16) & 1u);
    return (unsigned short)(u >> 16);
}
__device__ __forceinline__ float bf_f32(unsigned short h) {
    return __uint_as_float(((unsigned)h) << 16);
}
// pack two floats -> (hi bf16 pair, lo bf16 pair)
__device__ __forceinline__ uint2 cvt_pair(float f0, float f1) {
    unsigned short h0 = bf_rne(f0);
    unsigned short h1 = bf_rne(f1);
    uint2 r;
    r.x = (unsigned)h0 | ((unsigned)h1 << 16);
    r.y = (unsigned)bf_rne(f0 - bf_f32(h0)) | ((unsigned)bf_rne(f1 - bf_f32(h1)) << 16);
    return r;
}
union Cvt { u32x4 u; s16x8 s; };

// ---- W -> bf16 hi/lo planes, arranged in exact B-fragment order ----------
// elem index = ((it*4 + T)*64 + lane)*8 + j ; lane=(lq,ln): expert=16T+ln, k=32it+8lq+j
__global__ __launch_bounds__(256)
void wconv_kernel(const float* __restrict__ W, unsigned short* __restrict__ wpk,
                  int* __restrict__ wsI)
{
    unsigned tid = blockIdx.x * 256u + threadIdx.x;
    if (tid == 0) wsI[0] = 0;                 // counter zero (wconv precedes gemm)
    unsigned j    = tid & 7u;
    unsigned lane = (tid >> 3) & 63u;
    unsigned T    = (tid >> 9) & 3u;
    unsigned it   = tid >> 11;
    unsigned e = 16u * T + (lane & 15u);
    unsigned k = 32u * it + 8u * (lane >> 4) + j;
    float v = W[(size_t)e * DIM + k];
    unsigned short h = bf_rne(v);
    wpk[tid]            = h;
    wpk[WARR_U16 + tid] = bf_rne(v - bf_f32(h));
}

// ---- main: 8-wave within-block K-split GEMM + top-k ----------------------
// grid 1024 x 512 threads. Wave ws: 16 tokens (block tile) over K slice
// [ws*512, (ws+1)*512). Partials -> LDS -> fixed-order reduce -> top-k.
// A-frag straight from global (lane l: row ln, k contiguous). B-frag from
// precomputed wpk (L2-resident, fully coalesced).
__global__ __launch_bounds__(512, 8)
void gemm_topk_v3(const float* __restrict__ x,
                  const unsigned short* __restrict__ wpk,
                  float* __restrict__ out, int* __restrict__ wsI)
{
    __shared__ float part[WAVES][16][NE + 4];  // +4 pad: conflict-light writes
    __shared__ float outls[16][NE + 4];

    const int t    = threadIdx.x;
    const int ws   = t >> 6;
    const int l    = t & 63;
    const int lq   = l >> 4;
    const int ln   = l & 15;
    const int tok0 = blockIdx.x * 16;

    const float* xg = x + (size_t)(tok0 + ln) * DIM + ws * KSL + 8 * lq;
    const s16x8* bhp = (const s16x8*)wpk + ws * NITW * 256 + l;
    const s16x8* blp = bhp + (WARR_U16 / 8);

    f32x4 acc[4];
#pragma unroll
    for (int T = 0; T < 4; ++T) acc[T] = (f32x4){0.f, 0.f, 0.f, 0.f};

    // x pipeline depth 2
    float4 xa0 = *(const float4*)(xg + 0);
    float4 xa1 = *(const float4*)(xg + 4);
    float4 xb0 = *(const float4*)(xg + KB + 0);
    float4 xb1 = *(const float4*)(xg + KB + 4);
    // B pipeline depth 1
    s16x8 bh0 = bhp[0], bh1 = bhp[64], bh2 = bhp[128], bh3 = bhp[192];
    s16x8 bl0 = blp[0], bl1 = blp[64], bl2 = blp[128], bl3 = blp[192];

#pragma unroll 2
    for (int it = 0; it < NITW; ++it) {
        const int itx = (it + 2 < NITW) ? it + 2 : NITW - 1;
        const float* xp = xg + (size_t)KB * itx;
        float4 xn0 = *(const float4*)(xp + 0);
        float4 xn1 = *(const float4*)(xp + 4);

        const int itn = (it + 1 < NITW) ? it + 1 : NITW - 1;
        const s16x8* nhp = bhp + itn * 256;
        const s16x8* nlp = blp + itn * 256;
        s16x8 nh0 = nhp[0], nh1 = nhp[64], nh2 = nhp[128], nh3 = nhp[192];
        s16x8 nl0 = nlp[0], nl1 = nlp[64], nl2 = nlp[128], nl3 = nlp[192];

        // fp32 -> bf16 hi/lo in registers
        uint2 p0 = cvt_pair(xa0.x, xa0.y);
        uint2 p1 = cvt_pair(xa0.z, xa0.w);
        uint2 p2 = cvt_pair(xa1.x, xa1.y);
        uint2 p3 = cvt_pair(xa1.z, xa1.w);
        Cvt ch, cl;
        ch.u = (u32x4){p0.x, p1.x, p2.x, p3.x};
        cl.u = (u32x4){p0.y, p1.y, p2.y, p3.y};
        s16x8 ah = ch.s, al = cl.s;

        // bf16x3: ah*bh + ah*bl + al*bh ; 4 independent acc chains
        acc[0] = __builtin_amdgcn_mfma_f32_16x16x32_bf16(ah, bh0, acc[0], 0, 0, 0);
        acc[1] = __builtin_amdgcn_mfma_f32_16x16x32_bf16(ah, bh1, acc[1], 0, 0, 0);
        acc[2] = __builtin_amdgcn_mfma_f32_16x16x32_bf16(ah, bh2, acc[2], 0, 0, 0);
        acc[3] = __builtin_amdgcn_mfma_f32_16x16x32_bf16(ah, bh3, acc[3], 0, 0, 0);
        acc[0] = __builtin_amdgcn_mfma_f32_16x16x32_bf16(ah, bl0, acc[0], 0, 0, 0);
        acc[1] = __builtin_amdgcn_mfma_f32_16x16x32_bf16(ah, bl1, acc[1], 0, 0, 0);
        acc[2] = __builtin_amdgcn_mfma_f32_16x16x32_bf16(ah, bl2, acc[2], 0, 0, 0);
        acc[3] = __builtin_amdgcn_mfma_f32_16x16x32_bf16(ah, bl3, acc[3], 0, 0, 0);
        acc[0] = __builtin_amdgcn_mfma_f32_16x16x32_bf16(al, bh0, acc[0], 0, 0, 0);
        acc[1] = __builtin_amdgcn_mfma_f32_16x16x32_bf16(al, bh1, acc[1], 0, 0, 0);
        acc[2] = __builtin_amdgcn_mfma_f32_16x16x32_bf16(al, bh2, acc[2], 0, 0, 0);
        acc[3] = __builtin_amdgcn_mfma_f32_16x16x32_bf16(al, bh3, acc[3], 0, 0, 0);

        bh0 = nh0; bh1 = nh1; bh2 = nh2; bh3 = nh3;
        bl0 = nl0; bl1 = nl1; bl2 = nl2; bl3 = nl3;
        xa0 = xb0; xa1 = xb1; xb0 = xn0; xb1 = xn1;
    }

    // D layout (m89-verified): col = ln, row = 4*lq + r
#pragma unroll
    for (int T = 0; T < 4; ++T)
#pragma unroll
        for (int r = 0; r < 4; ++r)
            part[ws][4 * lq + r][16 * T + ln] = acc[T][r];
    __syncthreads();

    // fixed-order cross-wave reduce: 1024 outputs / 512 threads = 2 each
    for (int o = t; o < 16 * NE; o += 512) {
        const int ti = o >> 6, e = o & 63;
        float s = 0.f;
#pragma unroll
        for (int w2 = 0; w2 < WAVES; ++w2) s += part[w2][ti][e];
        outls[ti][e] = s;
    }
    __syncthreads();

    // top-9 scan + gap flag + fp32 softmax: one thread per token
    if (t < 16) {
        const int tok = tok0 + t;
        float v[9]; int idx[9];
#pragma unroll
        for (int j = 0; j < 9; ++j) {
            float best = -3.4e38f; int bi = 0;
            for (int e = 0; e < NE; ++e) {
                float q = outls[t][e];
                if (q > best) { best = q; bi = e; }   // lowest index wins ties
            }
            v[j] = best; idx[j] = bi;
            outls[t][bi] = -3.4e38f;
        }
        bool flag = false;
#pragma unroll
        for (int j = 0; j < 8; ++j)
            if (v[j] - v[j + 1] < GAPTH) flag = true;

        float m = v[0], s = 0.f, ex[8];
#pragma unroll
        for (int j = 0; j < 8; ++j) { ex[j] = expf(v[j] - m); s += ex[j]; }
        float inv = 1.f / s;
#pragma unroll
        for (int j = 0; j < 8; ++j) {
            out[(size_t)tok * TOPK + j] = ex[j] * inv;
            out[(size_t)TOKENS * TOPK + (size_t)tok * TOPK + j] = (float)idx[j];
        }
        if (flag) {
            int pos = atomicAdd(wsI, 1);
            if (pos < LISTCAP) wsI[16 + pos] = tok;
        }
    }
}

// exact fp64 recompute for flagged tokens (no MFMA-layout risk)
__global__ __launch_bounds__(256)
void refine_kernel(const float* __restrict__ x, const float* __restrict__ W,
                   float* __restrict__ out, const int* __restrict__ wsI)
{
    __shared__ float  xr[DIM];     // 16 KB
    __shared__ double pt[256];
    __shared__ double lg[NE];

    int cnt = wsI[0];
    if (cnt > LISTCAP) cnt = LISTCAP;
    const int t = threadIdx.x;

    for (int g = blockIdx.x; g < cnt; g += gridDim.x) {
        const int tok = wsI[16 + g];
        __syncthreads();   // previous iteration fully done before restaging
        for (int i = t; i < DIM / 4; i += 256)
            *(float4*)&xr[4 * i] = *(const float4*)&x[(size_t)tok * DIM + 4 * i];
        __syncthreads();

        const int e  = t & 63;
        const int ks = t >> 6;
        const float* wp = W + (size_t)e * DIM + ks * 1024;
        const float* xp = xr + ks * 1024;
        double p = 0.0;
        for (int i = 0; i < 256; ++i) {
            float4 wv = *(const float4*)&wp[4 * i];
            float4 xv = *(const float4*)&xp[4 * i];
            p = fma((double)xv.x, (double)wv.x, p);
            p = fma((double)xv.y, (double)wv.y, p);
            p = fma((double)xv.z, (double)wv.z, p);
            p = fma((double)xv.w, (double)wv.w, p);
        }
        pt[t] = p;
        __syncthreads();
        if (t < NE)
            lg[t] = ((pt[t] + pt[t + 64]) + pt[t + 128]) + pt[t + 192];  // fixed order
        __syncthreads();
        if (t == 0) {
            double vv[8]; int ii[8];
#pragma unroll
            for (int j = 0; j < 8; ++j) {
                double best = -1e300; int bi = 0;
                for (int e2 = 0; e2 < NE; ++e2) {
                    double q = lg[e2];
                    if (q > best) { best = q; bi = e2; }
                }
                vv[j] = best; ii[j] = bi;
                lg[bi] = -1e300;
            }
            float pf[8], ex[8], s = 0.f;
#pragma unroll
            for (int j = 0; j < 8; ++j) pf[j] = (float)vv[j];
            float m = pf[0];
#pragma unroll
            for (int j = 0; j < 8; ++j) { ex[j] = expf(pf[j] - m); s += ex[j]; }
            float inv = 1.f / s;
#pragma unroll
            for (int j = 0; j < 8; ++j) {
                out[(size_t)tok * TOPK + j] = ex[j] * inv;
                out[(size_t)TOKENS * TOPK + (size_t)tok * TOPK + j] = (float)ii[j];
            }
        }
    }
}

// =================== fallback (previous verified path) ====================
__global__ void zero_cnt_kernel(int* wsI) { if (threadIdx.x == 0) wsI[0] = 0; }

__global__ __launch_bounds__(256)
void gemm_topk_old(const float* __restrict__ x, const float* __restrict__ W,
                   float* __restrict__ out, int* __restrict__ wsI)
{
    __shared__ __align__(16) unsigned short frag[8192];
    __shared__ float ls[64][NE + 4];

    const int t    = threadIdx.x;
    const int tok0 = blockIdx.x * 64;

    const int srow = t >> 2;
    const int sq   = t & 3;
    const int sn   = srow & 15;
    const int sT   = srow >> 4;
    const int sdst = sT * 512 + (16 * sq + (sn ^ (2 * sq))) * 8;
    const float* xg = x + (size_t)(tok0 + srow) * DIM + 8 * sq;
    const float* wg = W + (size_t)srow * DIM + 8 * sq;

    const int w  = t >> 6;
    const int l  = t & 63;
    const int lq = l >> 4;
    const int ln = l & 15;
    const int fo = (16 * lq + (ln ^ (2 * lq))) * 8;

    f32x4 acc[4];
#pragma unroll
    for (int T = 0; T < 4; ++T) acc[T] = (f32x4){0.f, 0.f, 0.f, 0.f};

    float4 xa = *(const float4*)xg;
    float4 xb = *(const float4*)(xg + 4);
    float4 wa = *(const float4*)wg;
    float4 wb = *(const float4*)(wg + 4);

    for (int it = 0; it < NIT; ++it) {
        __syncthreads();
        {
            float vx[8] = {xa.x, xa.y, xa.z, xa.w, xb.x, xb.y, xb.z, xb.w};
            float vw[8] = {wa.x, wa.y, wa.z, wa.w, wb.x, wb.y, wb.z, wb.w};
            u16x8 vxh, vxl, vwh, vwl;
#pragma unroll
            for (int j = 0; j < 8; ++j) {
                unsigned short h1 = bf_rne(vx[j]);
                vxh[j] = h1;
                vxl[j] = bf_rne(vx[j] - bf_f32(h1));
                unsigned short h2 = bf_rne(vw[j]);
                vwh[j] = h2;
                vwl[j] = bf_rne(vw[j] - bf_f32(h2));
            }
            *(u16x8*)&frag[   0 + sdst] = vxh;
            *(u16x8*)&frag[2048 + sdst] = vxl;
            *(u16x8*)&frag[4096 + sdst] = vwh;
            *(u16x8*)&frag[6144 + sdst] = vwl;
        }
        __syncthreads();
        if (it + 1 < NIT) {
            const float* xp = xg + (size_t)(it + 1) * KB;
            const float* wp = wg + (size_t)(it + 1) * KB;
            xa = *(const float4*)xp;  xb = *(const float4*)(xp + 4);
            wa = *(const float4*)wp;  wb = *(const float4*)(wp + 4);
        }
        s16x8 ah = *(const s16x8*)&frag[   0 + w * 512 + fo];
        s16x8 al = *(const s16x8*)&frag[2048 + w * 512 + fo];
#pragma unroll
        for (int T = 0; T < 4; ++T) {
            s16x8 bh = *(const s16x8*)&frag[4096 + T * 512 + fo];
            s16x8 bl = *(const s16x8*)&frag[6144 + T * 512 + fo];
            acc[T] = __builtin_amdgcn_mfma_f32_16x16x32_bf16(ah, bh, acc[T], 0, 0, 0);
            acc[T] = __builtin_amdgcn_mfma_f32_16x16x32_bf16(ah, bl, acc[T], 0, 0, 0);
            acc[T] = __builtin_amdgcn_mfma_f32_16x16x32_bf16(al, bh, acc[T], 0, 0, 0);
        }
    }

    __syncthreads();
#pragma unroll
    for (int T = 0; T < 4; ++T)
#pragma unroll
        for (int r = 0; r < 4; ++r)
            ls[16 * w + 4 * lq + r][16 * T + ln] = acc[T][r];
    __syncthreads();

    if (t < 64) {
        const int tok = tok0 + t;
        float v[9]; int idx[9];
#pragma unroll
        for (int j = 0; j < 9; ++j) {
            float best = -3.4e38f; int bi = 0;
            for (int e = 0; e < NE; ++e) {
                float q = ls[t][e];
                if (q > best) { best = q; bi = e; }
            }
            v[j] = best; idx[j] = bi;
            ls[t][bi] = -3.4e38f;
        }
        bool flag = false;
#pragma unroll
        for (int j = 0; j < 8; ++j)
            if (v[j] - v[j + 1] < GAPTH) flag = true;

        float m = v[0], s = 0.f, ex[8];
#pragma unroll
        for (int j = 0; j < 8; ++j) { ex[j] = expf(v[j] - m); s += ex[j]; }
        float inv = 1.f / s;
#pragma unroll
        for (int j = 0; j < 8; ++j) {
            out[(size_t)tok * TOPK + j] = ex[j] * inv;
            out[(size_t)TOKENS * TOPK + (size_t)tok * TOPK + j] = (float)idx[j];
        }
        if (flag) {
            int pos = atomicAdd(wsI, 1);
            if (pos < LISTCAP) wsI[16 + pos] = tok;
        }
    }
}

extern "C" void kernel_launch(void* const* d_in, const int* in_sizes, int n_in,
                              void* d_out, int out_size, void* d_ws, size_t ws_size,
                              hipStream_t stream)
{
    const float* x = (const float*)d_in[0];
    const float* W = (const float*)d_in[1];
    float* out = (float*)d_out;

    if (ws_size >= WS_NEEDED) {
        unsigned short* wpk = (unsigned short*)d_ws;
        int* wsI = (int*)((char*)d_ws + WS_INT_OFF);
        hipLaunchKernelGGL(wconv_kernel, dim3(WARR_U16 / 256), dim3(256), 0, stream, W, wpk, wsI);
        hipLaunchKernelGGL(gemm_topk_v3, dim3(TOKENS / 16), dim3(512), 0, stream, x, wpk, out, wsI);
        hipLaunchKernelGGL(refine_kernel, dim3(256), dim3(256), 0, stream, x, W, out, wsI);
    } else {
        int* wsI = (int*)d_ws;
        hipLaunchKernelGGL(zero_cnt_kernel, dim3(1), dim3(64), 0, stream, wsI);
        hipLaunchKernelGGL(gemm_topk_old, dim3(TOKENS / 64), dim3(256), 0, stream, x, W, out, wsI);
        hipLaunchKernelGGL(refine_kernel, dim3(256), dim3(256), 0, stream, x, W, out, wsI);
    }
}

// Round 3
// 438.508 us; speedup vs baseline: 1.1491x; 1.1171x over previous
//
#include <hip/hip_runtime.h>
#include <math.h>

typedef float  f32x4 __attribute__((ext_vector_type(4)));
typedef short  s16x8 __attribute__((ext_vector_type(8)));
typedef unsigned short u16x8 __attribute__((ext_vector_type(8)));
typedef unsigned int   u32x4 __attribute__((ext_vector_type(4)));

constexpr int TOKENS  = 16384;
constexpr int DIM     = 4096;
constexpr int NE      = 64;
constexpr int TOPK    = 8;
constexpr int KB      = 32;          // k per chunk
constexpr int NIT     = DIM / KB;    // 128 chunks total
constexpr int WAVES   = 8;           // within-block K-split factor
constexpr int KSL     = DIM / WAVES; // 512 floats per wave slice
constexpr int NITW    = KSL / KB;    // 16 chunks per wave
constexpr int LISTCAP = 16384;
constexpr float GAPTH = 1e-4f;       // flag threshold (phase-1 err ~2e-5)

// precomputed W bf16 planes: [it][T][lane][8] ushorts, hi plane then lo plane
constexpr unsigned WARR_U16   = (unsigned)NIT * 4 * 64 * 8;                 // 262144
constexpr size_t   WS_INT_OFF = (size_t)WARR_U16 * 2 * sizeof(unsigned short); // 1 MiB
constexpr size_t   WS_NEEDED  = WS_INT_OFF + sizeof(int) * (size_t)(16 + LISTCAP);

__device__ __forceinline__ unsigned short bf_rne(float f) {
    unsigned u = __float_as_uint(f);
    u += 0x7FFFu + ((u >> 16) & 1u);
    return (unsigned short)(u >> 16);
}
__device__ __forceinline__ float bf_f32(unsigned short h) {
    return __uint_as_float(((unsigned)h) << 16);
}
// pack two floats -> (hi bf16 pair, lo bf16 pair)
__device__ __forceinline__ uint2 cvt_pair(float f0, float f1) {
    unsigned short h0 = bf_rne(f0);
    unsigned short h1 = bf_rne(f1);
    uint2 r;
    r.x = (unsigned)h0 | ((unsigned)h1 << 16);
    r.y = (unsigned)bf_rne(f0 - bf_f32(h0)) | ((unsigned)bf_rne(f1 - bf_f32(h1)) << 16);
    return r;
}
union Cvt { u32x4 u; s16x8 s; };

// ---- W -> bf16 hi/lo planes, arranged in exact B-fragment order ----------
// elem index = ((it*4 + T)*64 + lane)*8 + j ; lane=(lq,ln): expert=16T+ln, k=32it+8lq+j
__global__ __launch_bounds__(256)
void wconv_kernel(const float* __restrict__ W, unsigned short* __restrict__ wpk,
                  int* __restrict__ wsI)
{
    unsigned tid = blockIdx.x * 256u + threadIdx.x;
    if (tid == 0) wsI[0] = 0;                 // counter zero (wconv precedes gemm)
    unsigned j    = tid & 7u;
    unsigned lane = (tid >> 3) & 63u;
    unsigned T    = (tid >> 9) & 3u;
    unsigned it   = tid >> 11;
    unsigned e = 16u * T + (lane & 15u);
    unsigned k = 32u * it + 8u * (lane >> 4) + j;
    float v = W[(size_t)e * DIM + k];
    unsigned short h = bf_rne(v);
    wpk[tid]            = h;
    wpk[WARR_U16 + tid] = bf_rne(v - bf_f32(h));
}

// ---- main: 8-wave within-block K-split GEMM + top-k ----------------------
// grid 1024 x 512 threads, launch_bounds(512,4): 128-VGPR cap -> no spill,
// 2 blocks/CU co-resident = 16 waves/CU. Wave ws: 16 tokens over K slice
// [ws*512,(ws+1)*512). x: depth-2 register prefetch (HBM). B: loaded at use
// from L2-resident wpk; unroll-2 lets the scheduler hoist next-iter B loads
// into the MFMA shadow without dedicated prefetch registers.
__global__ __launch_bounds__(512, 4)
void gemm_topk_v4(const float* __restrict__ x,
                  const unsigned short* __restrict__ wpk,
                  float* __restrict__ out, int* __restrict__ wsI)
{
    __shared__ float part[WAVES][16][NE + 4];
    __shared__ float outls[16][NE + 4];

    const int t    = threadIdx.x;
    const int ws   = t >> 6;
    const int l    = t & 63;
    const int lq   = l >> 4;
    const int ln   = l & 15;
    const int tok0 = blockIdx.x * 16;

    const float* xg = x + (size_t)(tok0 + ln) * DIM + ws * KSL + 8 * lq;
    const s16x8* bhp = (const s16x8*)wpk + ws * NITW * 256 + l;
    const s16x8* blp = bhp + (WARR_U16 / 8);

    f32x4 acc[4];
#pragma unroll
    for (int T = 0; T < 4; ++T) acc[T] = (f32x4){0.f, 0.f, 0.f, 0.f};

    // x pipeline depth 2
    float4 xa0 = *(const float4*)(xg + 0);
    float4 xa1 = *(const float4*)(xg + 4);
    float4 xb0 = *(const float4*)(xg + KB + 0);
    float4 xb1 = *(const float4*)(xg + KB + 4);

#pragma unroll 2
    for (int it = 0; it < NITW; ++it) {
        // B fragments for current chunk (L2-resident; issued before x prefetch
        // and conversion so latency hides under them)
        const s16x8* hp = bhp + it * 256;
        const s16x8* lp = blp + it * 256;
        s16x8 bh0 = hp[0], bh1 = hp[64], bh2 = hp[128], bh3 = hp[192];
        s16x8 bl0 = lp[0], bl1 = lp[64], bl2 = lp[128], bl3 = lp[192];

        // prefetch x chunk it+2 (HBM)
        const int itx = (it + 2 < NITW) ? it + 2 : NITW - 1;
        const float* xp = xg + (size_t)KB * itx;
        float4 xn0 = *(const float4*)(xp + 0);
        float4 xn1 = *(const float4*)(xp + 4);

        // fp32 -> bf16 hi/lo in registers
        uint2 p0 = cvt_pair(xa0.x, xa0.y);
        uint2 p1 = cvt_pair(xa0.z, xa0.w);
        uint2 p2 = cvt_pair(xa1.x, xa1.y);
        uint2 p3 = cvt_pair(xa1.z, xa1.w);
        Cvt ch, cl;
        ch.u = (u32x4){p0.x, p1.x, p2.x, p3.x};
        cl.u = (u32x4){p0.y, p1.y, p2.y, p3.y};
        s16x8 ah = ch.s, al = cl.s;

        // bf16x3: ah*bh + ah*bl + al*bh ; 4 independent acc chains
        acc[0] = __builtin_amdgcn_mfma_f32_16x16x32_bf16(ah, bh0, acc[0], 0, 0, 0);
        acc[1] = __builtin_amdgcn_mfma_f32_16x16x32_bf16(ah, bh1, acc[1], 0, 0, 0);
        acc[2] = __builtin_amdgcn_mfma_f32_16x16x32_bf16(ah, bh2, acc[2], 0, 0, 0);
        acc[3] = __builtin_amdgcn_mfma_f32_16x16x32_bf16(ah, bh3, acc[3], 0, 0, 0);
        acc[0] = __builtin_amdgcn_mfma_f32_16x16x32_bf16(ah, bl0, acc[0], 0, 0, 0);
        acc[1] = __builtin_amdgcn_mfma_f32_16x16x32_bf16(ah, bl1, acc[1], 0, 0, 0);
        acc[2] = __builtin_amdgcn_mfma_f32_16x16x32_bf16(ah, bl2, acc[2], 0, 0, 0);
        acc[3] = __builtin_amdgcn_mfma_f32_16x16x32_bf16(ah, bl3, acc[3], 0, 0, 0);
        acc[0] = __builtin_amdgcn_mfma_f32_16x16x32_bf16(al, bh0, acc[0], 0, 0, 0);
        acc[1] = __builtin_amdgcn_mfma_f32_16x16x32_bf16(al, bh1, acc[1], 0, 0, 0);
        acc[2] = __builtin_amdgcn_mfma_f32_16x16x32_bf16(al, bh2, acc[2], 0, 0, 0);
        acc[3] = __builtin_amdgcn_mfma_f32_16x16x32_bf16(al, bh3, acc[3], 0, 0, 0);

        xa0 = xb0; xa1 = xb1; xb0 = xn0; xb1 = xn1;
    }

    // D layout (m89-verified): col = ln, row = 4*lq + r
#pragma unroll
    for (int T = 0; T < 4; ++T)
#pragma unroll
        for (int r = 0; r < 4; ++r)
            part[ws][4 * lq + r][16 * T + ln] = acc[T][r];
    __syncthreads();

    // fixed-order cross-wave reduce: 1024 outputs / 512 threads = 2 each
    for (int o = t; o < 16 * NE; o += 512) {
        const int ti = o >> 6, e = o & 63;
        float s = 0.f;
#pragma unroll
        for (int w2 = 0; w2 < WAVES; ++w2) s += part[w2][ti][e];
        outls[ti][e] = s;
    }
    __syncthreads();

    // top-9 scan + gap flag + fp32 softmax: one thread per token
    if (t < 16) {
        const int tok = tok0 + t;
        float v[9]; int idx[9];
#pragma unroll
        for (int j = 0; j < 9; ++j) {
            float best = -3.4e38f; int bi = 0;
            for (int e = 0; e < NE; ++e) {
                float q = outls[t][e];
                if (q > best) { best = q; bi = e; }   // lowest index wins ties
            }
            v[j] = best; idx[j] = bi;
            outls[t][bi] = -3.4e38f;
        }
        bool flag = false;
#pragma unroll
        for (int j = 0; j < 8; ++j)
            if (v[j] - v[j + 1] < GAPTH) flag = true;

        float m = v[0], s = 0.f, ex[8];
#pragma unroll
        for (int j = 0; j < 8; ++j) { ex[j] = expf(v[j] - m); s += ex[j]; }
        float inv = 1.f / s;
#pragma unroll
        for (int j = 0; j < 8; ++j) {
            out[(size_t)tok * TOPK + j] = ex[j] * inv;
            out[(size_t)TOKENS * TOPK + (size_t)tok * TOPK + j] = (float)idx[j];
        }
        if (flag) {
            int pos = atomicAdd(wsI, 1);
            if (pos < LISTCAP) wsI[16 + pos] = tok;
        }
    }
}

// exact fp64 recompute for flagged tokens (no MFMA-layout risk)
__global__ __launch_bounds__(256)
void refine_kernel(const float* __restrict__ x, const float* __restrict__ W,
                   float* __restrict__ out, const int* __restrict__ wsI)
{
    __shared__ float  xr[DIM];     // 16 KB
    __shared__ double pt[256];
    __shared__ double lg[NE];

    int cnt = wsI[0];
    if (cnt > LISTCAP) cnt = LISTCAP;
    const int t = threadIdx.x;

    for (int g = blockIdx.x; g < cnt; g += gridDim.x) {
        const int tok = wsI[16 + g];
        __syncthreads();   // previous iteration fully done before restaging
        for (int i = t; i < DIM / 4; i += 256)
            *(float4*)&xr[4 * i] = *(const float4*)&x[(size_t)tok * DIM + 4 * i];
        __syncthreads();

        const int e  = t & 63;
        const int ks = t >> 6;
        const float* wp = W + (size_t)e * DIM + ks * 1024;
        const float* xp = xr + ks * 1024;
        double p = 0.0;
        for (int i = 0; i < 256; ++i) {
            float4 wv = *(const float4*)&wp[4 * i];
            float4 xv = *(const float4*)&xp[4 * i];
            p = fma((double)xv.x, (double)wv.x, p);
            p = fma((double)xv.y, (double)wv.y, p);
            p = fma((double)xv.z, (double)wv.z, p);
            p = fma((double)xv.w, (double)wv.w, p);
        }
        pt[t] = p;
        __syncthreads();
        if (t < NE)
            lg[t] = ((pt[t] + pt[t + 64]) + pt[t + 128]) + pt[t + 192];  // fixed order
        __syncthreads();
        if (t == 0) {
            double vv[8]; int ii[8];
#pragma unroll
            for (int j = 0; j < 8; ++j) {
                double best = -1e300; int bi = 0;
                for (int e2 = 0; e2 < NE; ++e2) {
                    double q = lg[e2];
                    if (q > best) { best = q; bi = e2; }
                }
                vv[j] = best; ii[j] = bi;
                lg[bi] = -1e300;
            }
            float pf[8], ex[8], s = 0.f;
#pragma unroll
            for (int j = 0; j < 8; ++j) pf[j] = (float)vv[j];
            float m = pf[0];
#pragma unroll
            for (int j = 0; j < 8; ++j) { ex[j] = expf(pf[j] - m); s += ex[j]; }
            float inv = 1.f / s;
#pragma unroll
            for (int j = 0; j < 8; ++j) {
                out[(size_t)tok * TOPK + j] = ex[j] * inv;
                out[(size_t)TOKENS * TOPK + (size_t)tok * TOPK + j] = (float)ii[j];
            }
        }
    }
}

// =================== fallback (previous verified path) ====================
__global__ void zero_cnt_kernel(int* wsI) { if (threadIdx.x == 0) wsI[0] = 0; }

__global__ __launch_bounds__(256)
void gemm_topk_old(const float* __restrict__ x, const float* __restrict__ W,
                   float* __restrict__ out, int* __restrict__ wsI)
{
    __shared__ __align__(16) unsigned short frag[8192];
    __shared__ float ls[64][NE + 4];

    const int t    = threadIdx.x;
    const int tok0 = blockIdx.x * 64;

    const int srow = t >> 2;
    const int sq   = t & 3;
    const int sn   = srow & 15;
    const int sT   = srow >> 4;
    const int sdst = sT * 512 + (16 * sq + (sn ^ (2 * sq))) * 8;
    const float* xg = x + (size_t)(tok0 + srow) * DIM + 8 * sq;
    const float* wg = W + (size_t)srow * DIM + 8 * sq;

    const int w  = t >> 6;
    const int l  = t & 63;
    const int lq = l >> 4;
    const int ln = l & 15;
    const int fo = (16 * lq + (ln ^ (2 * lq))) * 8;

    f32x4 acc[4];
#pragma unroll
    for (int T = 0; T < 4; ++T) acc[T] = (f32x4){0.f, 0.f, 0.f, 0.f};

    float4 xa = *(const float4*)xg;
    float4 xb = *(const float4*)(xg + 4);
    float4 wa = *(const float4*)wg;
    float4 wb = *(const float4*)(wg + 4);

    for (int it = 0; it < NIT; ++it) {
        __syncthreads();
        {
            float vx[8] = {xa.x, xa.y, xa.z, xa.w, xb.x, xb.y, xb.z, xb.w};
            float vw[8] = {wa.x, wa.y, wa.z, wa.w, wb.x, wb.y, wb.z, wb.w};
            u16x8 vxh, vxl, vwh, vwl;
#pragma unroll
            for (int j = 0; j < 8; ++j) {
                unsigned short h1 = bf_rne(vx[j]);
                vxh[j] = h1;
                vxl[j] = bf_rne(vx[j] - bf_f32(h1));
                unsigned short h2 = bf_rne(vw[j]);
                vwh[j] = h2;
                vwl[j] = bf_rne(vw[j] - bf_f32(h2));
            }
            *(u16x8*)&frag[   0 + sdst] = vxh;
            *(u16x8*)&frag[2048 + sdst] = vxl;
            *(u16x8*)&frag[4096 + sdst] = vwh;
            *(u16x8*)&frag[6144 + sdst] = vwl;
        }
        __syncthreads();
        if (it + 1 < NIT) {
            const float* xp = xg + (size_t)(it + 1) * KB;
            const float* wp = wg + (size_t)(it + 1) * KB;
            xa = *(const float4*)xp;  xb = *(const float4*)(xp + 4);
            wa = *(const float4*)wp;  wb = *(const float4*)(wp + 4);
        }
        s16x8 ah = *(const s16x8*)&frag[   0 + w * 512 + fo];
        s16x8 al = *(const s16x8*)&frag[2048 + w * 512 + fo];
#pragma unroll
        for (int T = 0; T < 4; ++T) {
            s16x8 bh = *(const s16x8*)&frag[4096 + T * 512 + fo];
            s16x8 bl = *(const s16x8*)&frag[6144 + T * 512 + fo];
            acc[T] = __builtin_amdgcn_mfma_f32_16x16x32_bf16(ah, bh, acc[T], 0, 0, 0);
            acc[T] = __builtin_amdgcn_mfma_f32_16x16x32_bf16(ah, bl, acc[T], 0, 0, 0);
            acc[T] = __builtin_amdgcn_mfma_f32_16x16x32_bf16(al, bh, acc[T], 0, 0, 0);
        }
    }

    __syncthreads();
#pragma unroll
    for (int T = 0; T < 4; ++T)
#pragma unroll
        for (int r = 0; r < 4; ++r)
            ls[16 * w + 4 * lq + r][16 * T + ln] = acc[T][r];
    __syncthreads();

    if (t < 64) {
        const int tok = tok0 + t;
        float v[9]; int idx[9];
#pragma unroll
        for (int j = 0; j < 9; ++j) {
            float best = -3.4e38f; int bi = 0;
            for (int e = 0; e < NE; ++e) {
                float q = ls[t][e];
                if (q > best) { best = q; bi = e; }
            }
            v[j] = best; idx[j] = bi;
            ls[t][bi] = -3.4e38f;
        }
        bool flag = false;
#pragma unroll
        for (int j = 0; j < 8; ++j)
            if (v[j] - v[j + 1] < GAPTH) flag = true;

        float m = v[0], s = 0.f, ex[8];
#pragma unroll
        for (int j = 0; j < 8; ++j) { ex[j] = expf(v[j] - m); s += ex[j]; }
        float inv = 1.f / s;
#pragma unroll
        for (int j = 0; j < 8; ++j) {
            out[(size_t)tok * TOPK + j] = ex[j] * inv;
            out[(size_t)TOKENS * TOPK + (size_t)tok * TOPK + j] = (float)idx[j];
        }
        if (flag) {
            int pos = atomicAdd(wsI, 1);
            if (pos < LISTCAP) wsI[16 + pos] = tok;
        }
    }
}

extern "C" void kernel_launch(void* const* d_in, const int* in_sizes, int n_in,
                              void* d_out, int out_size, void* d_ws, size_t ws_size,
                              hipStream_t stream)
{
    const float* x = (const float*)d_in[0];
    const float* W = (const float*)d_in[1];
    float* out = (float*)d_out;

    if (ws_size >= WS_NEEDED) {
        unsigned short* wpk = (unsigned short*)d_ws;
        int* wsI = (int*)((char*)d_ws + WS_INT_OFF);
        hipLaunchKernelGGL(wconv_kernel, dim3(WARR_U16 / 256), dim3(256), 0, stream, W, wpk, wsI);
        hipLaunchKernelGGL(gemm_topk_v4, dim3(TOKENS / 16), dim3(512), 0, stream, x, wpk, out, wsI);
        hipLaunchKernelGGL(refine_kernel, dim3(256), dim3(256), 0, stream, x, W, out, wsI);
    } else {
        int* wsI = (int*)d_ws;
        hipLaunchKernelGGL(zero_cnt_kernel, dim3(1), dim3(64), 0, stream, wsI);
        hipLaunchKernelGGL(gemm_topk_old, dim3(TOKENS / 64), dim3(256), 0, stream, x, W, out, wsI);
        hipLaunchKernelGGL(refine_kernel, dim3(256), dim3(256), 0, stream, x, W, out, wsI);
    }
}

// Round 4
// 436.736 us; speedup vs baseline: 1.1538x; 1.0041x over previous
//
#include <hip/hip_runtime.h>
#include <math.h>

typedef float  f32x4 __attribute__((ext_vector_type(4)));
typedef short  s16x8 __attribute__((ext_vector_type(8)));
typedef unsigned short u16x8 __attribute__((ext_vector_type(8)));
typedef unsigned int   u32x4 __attribute__((ext_vector_type(4)));

constexpr int TOKENS  = 16384;
constexpr int DIM     = 4096;
constexpr int NE      = 64;
constexpr int TOPK    = 8;
constexpr int KB      = 32;          // k per chunk
constexpr int NIT     = DIM / KB;    // 128 chunks total
constexpr int WAVES   = 8;           // within-block K-split factor
constexpr int KSL     = DIM / WAVES; // 512 floats per wave slice
constexpr int NITW    = KSL / KB;    // 16 chunks per wave
constexpr int LISTCAP = 16384;
constexpr float GAPTH = 1e-4f;       // flag threshold (phase-1 err ~2e-5)

// precomputed W bf16 planes: [it][T][lane][8] ushorts, hi plane then lo plane
constexpr unsigned WARR_U16   = (unsigned)NIT * 4 * 64 * 8;                 // 262144
constexpr size_t   WS_INT_OFF = (size_t)WARR_U16 * 2 * sizeof(unsigned short); // 1 MiB
constexpr size_t   WS_NEEDED  = WS_INT_OFF + sizeof(int) * (size_t)(16 + LISTCAP);

__device__ __forceinline__ unsigned short bf_rne(float f) {
    unsigned u = __float_as_uint(f);
    u += 0x7FFFu + ((u >> 16) & 1u);
    return (unsigned short)(u >> 16);
}
__device__ __forceinline__ float bf_f32(unsigned short h) {
    return __uint_as_float(((unsigned)h) << 16);
}
// pack two floats -> (hi bf16 pair, lo bf16 pair)
__device__ __forceinline__ uint2 cvt_pair(float f0, float f1) {
    unsigned short h0 = bf_rne(f0);
    unsigned short h1 = bf_rne(f1);
    uint2 r;
    r.x = (unsigned)h0 | ((unsigned)h1 << 16);
    r.y = (unsigned)bf_rne(f0 - bf_f32(h0)) | ((unsigned)bf_rne(f1 - bf_f32(h1)) << 16);
    return r;
}
union Cvt { u32x4 u; s16x8 s; };

// ---- W -> bf16 hi/lo planes, arranged in exact B-fragment order ----------
// elem index = ((it*4 + T)*64 + lane)*8 + j ; lane=(lq,ln): expert=16T+ln, k=32it+8lq+j
__global__ __launch_bounds__(256)
void wconv_kernel(const float* __restrict__ W, unsigned short* __restrict__ wpk,
                  int* __restrict__ wsI)
{
    unsigned tid = blockIdx.x * 256u + threadIdx.x;
    if (tid == 0) wsI[0] = 0;                 // counter zero (wconv precedes gemm)
    unsigned j    = tid & 7u;
    unsigned lane = (tid >> 3) & 63u;
    unsigned T    = (tid >> 9) & 3u;
    unsigned it   = tid >> 11;
    unsigned e = 16u * T + (lane & 15u);
    unsigned k = 32u * it + 8u * (lane >> 4) + j;
    float v = W[(size_t)e * DIM + k];
    unsigned short h = bf_rne(v);
    wpk[tid]            = h;
    wpk[WARR_U16 + tid] = bf_rne(v - bf_f32(h));
}

// ---- main: 8-wave within-block K-split GEMM + top-k ----------------------
// grid 1024 x 512 threads, launch_bounds(512,4): 128-VGPR cap. v5: NO loop
// unroll (unroll-2 doubled B/x live ranges -> spill inside the 128 cap was
// the v4 residual). Live state ~100 VGPR: acc 16 + B 32 + x-pipe 24 +
// cvt temps + running pointers. Per-iter exposed B-latency (~250cy L2 minus
// ~180cy independent cvt VALU) is covered by 4 waves/SIMD.
__global__ __launch_bounds__(512, 4)
void gemm_topk_v5(const float* __restrict__ x,
                  const unsigned short* __restrict__ wpk,
                  float* __restrict__ out, int* __restrict__ wsI)
{
    __shared__ float part[WAVES][16][NE + 4];
    __shared__ float outls[16][NE + 4];

    const int t    = threadIdx.x;
    const int ws   = t >> 6;
    const int l    = t & 63;
    const int lq   = l >> 4;
    const int ln   = l & 15;
    const int tok0 = blockIdx.x * 16;

    const float* xg = x + (size_t)(tok0 + ln) * DIM + ws * KSL + 8 * lq;
    const s16x8* bp = (const s16x8*)wpk + ws * NITW * 256 + l;   // hi plane, running
    const float* xq = xg + 2 * KB;                               // prefetch cursor

    f32x4 acc[4];
#pragma unroll
    for (int T = 0; T < 4; ++T) acc[T] = (f32x4){0.f, 0.f, 0.f, 0.f};

    // x pipeline depth 2
    float4 xa0 = *(const float4*)(xg + 0);
    float4 xa1 = *(const float4*)(xg + 4);
    float4 xb0 = *(const float4*)(xg + KB + 0);
    float4 xb1 = *(const float4*)(xg + KB + 4);

#pragma unroll 1
    for (int it = 0; it < NITW; ++it) {
        // B fragments for current chunk (L2-resident), single running pointer
        const s16x8* hp = bp;
        const s16x8* lp = bp + (WARR_U16 / 8);
        s16x8 bh0 = hp[0], bh1 = hp[64], bh2 = hp[128], bh3 = hp[192];
        s16x8 bl0 = lp[0], bl1 = lp[64], bl2 = lp[128], bl3 = lp[192];
        bp += 256;

        // prefetch x chunk it+2 (clamped at slice end)
        float4 xn0 = *(const float4*)(xq + 0);
        float4 xn1 = *(const float4*)(xq + 4);
        if (it + 3 < NITW) xq += KB;

        // fp32 -> bf16 hi/lo in registers
        uint2 p0 = cvt_pair(xa0.x, xa0.y);
        uint2 p1 = cvt_pair(xa0.z, xa0.w);
        uint2 p2 = cvt_pair(xa1.x, xa1.y);
        uint2 p3 = cvt_pair(xa1.z, xa1.w);
        Cvt ch, cl;
        ch.u = (u32x4){p0.x, p1.x, p2.x, p3.x};
        cl.u = (u32x4){p0.y, p1.y, p2.y, p3.y};
        s16x8 ah = ch.s, al = cl.s;

        // bf16x3: ah*bh + ah*bl + al*bh ; 4 independent acc chains
        acc[0] = __builtin_amdgcn_mfma_f32_16x16x32_bf16(ah, bh0, acc[0], 0, 0, 0);
        acc[1] = __builtin_amdgcn_mfma_f32_16x16x32_bf16(ah, bh1, acc[1], 0, 0, 0);
        acc[2] = __builtin_amdgcn_mfma_f32_16x16x32_bf16(ah, bh2, acc[2], 0, 0, 0);
        acc[3] = __builtin_amdgcn_mfma_f32_16x16x32_bf16(ah, bh3, acc[3], 0, 0, 0);
        acc[0] = __builtin_amdgcn_mfma_f32_16x16x32_bf16(ah, bl0, acc[0], 0, 0, 0);
        acc[1] = __builtin_amdgcn_mfma_f32_16x16x32_bf16(ah, bl1, acc[1], 0, 0, 0);
        acc[2] = __builtin_amdgcn_mfma_f32_16x16x32_bf16(ah, bl2, acc[2], 0, 0, 0);
        acc[3] = __builtin_amdgcn_mfma_f32_16x16x32_bf16(ah, bl3, acc[3], 0, 0, 0);
        acc[0] = __builtin_amdgcn_mfma_f32_16x16x32_bf16(al, bh0, acc[0], 0, 0, 0);
        acc[1] = __builtin_amdgcn_mfma_f32_16x16x32_bf16(al, bh1, acc[1], 0, 0, 0);
        acc[2] = __builtin_amdgcn_mfma_f32_16x16x32_bf16(al, bh2, acc[2], 0, 0, 0);
        acc[3] = __builtin_amdgcn_mfma_f32_16x16x32_bf16(al, bh3, acc[3], 0, 0, 0);

        xa0 = xb0; xa1 = xb1; xb0 = xn0; xb1 = xn1;
    }

    // D layout (m89-verified): col = ln, row = 4*lq + r
#pragma unroll
    for (int T = 0; T < 4; ++T)
#pragma unroll
        for (int r = 0; r < 4; ++r)
            part[ws][4 * lq + r][16 * T + ln] = acc[T][r];
    __syncthreads();

    // fixed-order cross-wave reduce: 1024 outputs / 512 threads = 2 each
    for (int o = t; o < 16 * NE; o += 512) {
        const int ti = o >> 6, e = o & 63;
        float s = 0.f;
#pragma unroll
        for (int w2 = 0; w2 < WAVES; ++w2) s += part[w2][ti][e];
        outls[ti][e] = s;
    }
    __syncthreads();

    // top-9 scan + gap flag + fp32 softmax: one thread per token
    if (t < 16) {
        const int tok = tok0 + t;
        float v[9]; int idx[9];
#pragma unroll
        for (int j = 0; j < 9; ++j) {
            float best = -3.4e38f; int bi = 0;
            for (int e = 0; e < NE; ++e) {
                float q = outls[t][e];
                if (q > best) { best = q; bi = e; }   // lowest index wins ties
            }
            v[j] = best; idx[j] = bi;
            outls[t][bi] = -3.4e38f;
        }
        bool flag = false;
#pragma unroll
        for (int j = 0; j < 8; ++j)
            if (v[j] - v[j + 1] < GAPTH) flag = true;

        float m = v[0], s = 0.f, ex[8];
#pragma unroll
        for (int j = 0; j < 8; ++j) { ex[j] = expf(v[j] - m); s += ex[j]; }
        float inv = 1.f / s;
#pragma unroll
        for (int j = 0; j < 8; ++j) {
            out[(size_t)tok * TOPK + j] = ex[j] * inv;
            out[(size_t)TOKENS * TOPK + (size_t)tok * TOPK + j] = (float)idx[j];
        }
        if (flag) {
            int pos = atomicAdd(wsI, 1);
            if (pos < LISTCAP) wsI[16 + pos] = tok;
        }
    }
}

// exact fp64 recompute for flagged tokens (no MFMA-layout risk)
__global__ __launch_bounds__(256)
void refine_kernel(const float* __restrict__ x, const float* __restrict__ W,
                   float* __restrict__ out, const int* __restrict__ wsI)
{
    __shared__ float  xr[DIM];     // 16 KB
    __shared__ double pt[256];
    __shared__ double lg[NE];

    int cnt = wsI[0];
    if (cnt > LISTCAP) cnt = LISTCAP;
    const int t = threadIdx.x;

    for (int g = blockIdx.x; g < cnt; g += gridDim.x) {
        const int tok = wsI[16 + g];
        __syncthreads();   // previous iteration fully done before restaging
        for (int i = t; i < DIM / 4; i += 256)
            *(float4*)&xr[4 * i] = *(const float4*)&x[(size_t)tok * DIM + 4 * i];
        __syncthreads();

        const int e  = t & 63;
        const int ks = t >> 6;
        const float* wp = W + (size_t)e * DIM + ks * 1024;
        const float* xp = xr + ks * 1024;
        double p = 0.0;
        for (int i = 0; i < 256; ++i) {
            float4 wv = *(const float4*)&wp[4 * i];
            float4 xv = *(const float4*)&xp[4 * i];
            p = fma((double)xv.x, (double)wv.x, p);
            p = fma((double)xv.y, (double)wv.y, p);
            p = fma((double)xv.z, (double)wv.z, p);
            p = fma((double)xv.w, (double)wv.w, p);
        }
        pt[t] = p;
        __syncthreads();
        if (t < NE)
            lg[t] = ((pt[t] + pt[t + 64]) + pt[t + 128]) + pt[t + 192];  // fixed order
        __syncthreads();
        if (t == 0) {
            double vv[8]; int ii[8];
#pragma unroll
            for (int j = 0; j < 8; ++j) {
                double best = -1e300; int bi = 0;
                for (int e2 = 0; e2 < NE; ++e2) {
                    double q = lg[e2];
                    if (q > best) { best = q; bi = e2; }
                }
                vv[j] = best; ii[j] = bi;
                lg[bi] = -1e300;
            }
            float pf[8], ex[8], s = 0.f;
#pragma unroll
            for (int j = 0; j < 8; ++j) pf[j] = (float)vv[j];
            float m = pf[0];
#pragma unroll
            for (int j = 0; j < 8; ++j) { ex[j] = expf(pf[j] - m); s += ex[j]; }
            float inv = 1.f / s;
#pragma unroll
            for (int j = 0; j < 8; ++j) {
                out[(size_t)tok * TOPK + j] = ex[j] * inv;
                out[(size_t)TOKENS * TOPK + (size_t)tok * TOPK + j] = (float)ii[j];
            }
        }
    }
}

// =================== fallback (previous verified path) ====================
__global__ void zero_cnt_kernel(int* wsI) { if (threadIdx.x == 0) wsI[0] = 0; }

__global__ __launch_bounds__(256)
void gemm_topk_old(const float* __restrict__ x, const float* __restrict__ W,
                   float* __restrict__ out, int* __restrict__ wsI)
{
    __shared__ __align__(16) unsigned short frag[8192];
    __shared__ float ls[64][NE + 4];

    const int t    = threadIdx.x;
    const int tok0 = blockIdx.x * 64;

    const int srow = t >> 2;
    const int sq   = t & 3;
    const int sn   = srow & 15;
    const int sT   = srow >> 4;
    const int sdst = sT * 512 + (16 * sq + (sn ^ (2 * sq))) * 8;
    const float* xg = x + (size_t)(tok0 + srow) * DIM + 8 * sq;
    const float* wg = W + (size_t)srow * DIM + 8 * sq;

    const int w  = t >> 6;
    const int l  = t & 63;
    const int lq = l >> 4;
    const int ln = l & 15;
    const int fo = (16 * lq + (ln ^ (2 * lq))) * 8;

    f32x4 acc[4];
#pragma unroll
    for (int T = 0; T < 4; ++T) acc[T] = (f32x4){0.f, 0.f, 0.f, 0.f};

    float4 xa = *(const float4*)xg;
    float4 xb = *(const float4*)(xg + 4);
    float4 wa = *(const float4*)wg;
    float4 wb = *(const float4*)(wg + 4);

    for (int it = 0; it < NIT; ++it) {
        __syncthreads();
        {
            float vx[8] = {xa.x, xa.y, xa.z, xa.w, xb.x, xb.y, xb.z, xb.w};
            float vw[8] = {wa.x, wa.y, wa.z, wa.w, wb.x, wb.y, wb.z, wb.w};
            u16x8 vxh, vxl, vwh, vwl;
#pragma unroll
            for (int j = 0; j < 8; ++j) {
                unsigned short h1 = bf_rne(vx[j]);
                vxh[j] = h1;
                vxl[j] = bf_rne(vx[j] - bf_f32(h1));
                unsigned short h2 = bf_rne(vw[j]);
                vwh[j] = h2;
                vwl[j] = bf_rne(vw[j] - bf_f32(h2));
            }
            *(u16x8*)&frag[   0 + sdst] = vxh;
            *(u16x8*)&frag[2048 + sdst] = vxl;
            *(u16x8*)&frag[4096 + sdst] = vwh;
            *(u16x8*)&frag[6144 + sdst] = vwl;
        }
        __syncthreads();
        if (it + 1 < NIT) {
            const float* xp = xg + (size_t)(it + 1) * KB;
            const float* wp = wg + (size_t)(it + 1) * KB;
            xa = *(const float4*)xp;  xb = *(const float4*)(xp + 4);
            wa = *(const float4*)wp;  wb = *(const float4*)(wp + 4);
        }
        s16x8 ah = *(const s16x8*)&frag[   0 + w * 512 + fo];
        s16x8 al = *(const s16x8*)&frag[2048 + w * 512 + fo];
#pragma unroll
        for (int T = 0; T < 4; ++T) {
            s16x8 bh = *(const s16x8*)&frag[4096 + T * 512 + fo];
            s16x8 bl = *(const s16x8*)&frag[6144 + T * 512 + fo];
            acc[T] = __builtin_amdgcn_mfma_f32_16x16x32_bf16(ah, bh, acc[T], 0, 0, 0);
            acc[T] = __builtin_amdgcn_mfma_f32_16x16x32_bf16(ah, bl, acc[T], 0, 0, 0);
            acc[T] = __builtin_amdgcn_mfma_f32_16x16x32_bf16(al, bh, acc[T], 0, 0, 0);
        }
    }

    __syncthreads();
#pragma unroll
    for (int T = 0; T < 4; ++T)
#pragma unroll
        for (int r = 0; r < 4; ++r)
            ls[16 * w + 4 * lq + r][16 * T + ln] = acc[T][r];
    __syncthreads();

    if (t < 64) {
        const int tok = tok0 + t;
        float v[9]; int idx[9];
#pragma unroll
        for (int j = 0; j < 9; ++j) {
            float best = -3.4e38f; int bi = 0;
            for (int e = 0; e < NE; ++e) {
                float q = ls[t][e];
                if (q > best) { best = q; bi = e; }
            }
            v[j] = best; idx[j] = bi;
            ls[t][bi] = -3.4e38f;
        }
        bool flag = false;
#pragma unroll
        for (int j = 0; j < 8; ++j)
            if (v[j] - v[j + 1] < GAPTH) flag = true;

        float m = v[0], s = 0.f, ex[8];
#pragma unroll
        for (int j = 0; j < 8; ++j) { ex[j] = expf(v[j] - m); s += ex[j]; }
        float inv = 1.f / s;
#pragma unroll
        for (int j = 0; j < 8; ++j) {
            out[(size_t)tok * TOPK + j] = ex[j] * inv;
            out[(size_t)TOKENS * TOPK + (size_t)tok * TOPK + j] = (float)idx[j];
        }
        if (flag) {
            int pos = atomicAdd(wsI, 1);
            if (pos < LISTCAP) wsI[16 + pos] = tok;
        }
    }
}

extern "C" void kernel_launch(void* const* d_in, const int* in_sizes, int n_in,
                              void* d_out, int out_size, void* d_ws, size_t ws_size,
                              hipStream_t stream)
{
    const float* x = (const float*)d_in[0];
    const float* W = (const float*)d_in[1];
    float* out = (float*)d_out;

    if (ws_size >= WS_NEEDED) {
        unsigned short* wpk = (unsigned short*)d_ws;
        int* wsI = (int*)((char*)d_ws + WS_INT_OFF);
        hipLaunchKernelGGL(wconv_kernel, dim3(WARR_U16 / 256), dim3(256), 0, stream, W, wpk, wsI);
        hipLaunchKernelGGL(gemm_topk_v5, dim3(TOKENS / 16), dim3(512), 0, stream, x, wpk, out, wsI);
        hipLaunchKernelGGL(refine_kernel, dim3(256), dim3(256), 0, stream, x, W, out, wsI);
    } else {
        int* wsI = (int*)d_ws;
        hipLaunchKernelGGL(zero_cnt_kernel, dim3(1), dim3(64), 0, stream, wsI);
        hipLaunchKernelGGL(gemm_topk_old, dim3(TOKENS / 64), dim3(256), 0, stream, x, W, out, wsI);
        hipLaunchKernelGGL(refine_kernel, dim3(256), dim3(256), 0, stream, x, W, out, wsI);
    }
}